// Round 8
// baseline (13114.075 us; speedup 1.0000x reference)
//
#include <hip/hip_runtime.h>
#include <cmath>

#define LEAK 0.95f
#define ILEAK 0.05f

typedef float f4 __attribute__((ext_vector_type(4)));
typedef unsigned long long ull;

// ---------------- Phase 1: u = x @ W_in^T (fp32 tiled GEMM) ----------------
__global__ __launch_bounds__(256) void resv_gemm_uin(
    const float* __restrict__ A, const float* __restrict__ Bm,
    float* __restrict__ C, int M, int N, int K)
{
    __shared__ float As[16][68];
    __shared__ float Bs[16][68];
    const int tid = threadIdx.x;
    const int m0 = blockIdx.y * 64;
    const int n0 = blockIdx.x * 64;
    const int lm = tid >> 2;
    const int lk = (tid & 3) * 4;
    const int ty = tid >> 4;
    const int tx = tid & 15;

    float acc[4][4];
#pragma unroll
    for (int i = 0; i < 4; ++i)
#pragma unroll
        for (int j = 0; j < 4; ++j) acc[i][j] = 0.f;

    const float* Aptr = A + (size_t)(m0 + lm) * K + lk;
    const float* Bptr = Bm + (size_t)(n0 + lm) * K + lk;

    for (int k0 = 0; k0 < K; k0 += 16) {
        float4 av = *(const float4*)(Aptr + k0);
        float4 bv = *(const float4*)(Bptr + k0);
        __syncthreads();
        As[lk + 0][lm] = av.x; As[lk + 1][lm] = av.y;
        As[lk + 2][lm] = av.z; As[lk + 3][lm] = av.w;
        Bs[lk + 0][lm] = bv.x; Bs[lk + 1][lm] = bv.y;
        Bs[lk + 2][lm] = bv.z; Bs[lk + 3][lm] = bv.w;
        __syncthreads();
#pragma unroll
        for (int kk = 0; kk < 16; ++kk) {
            float4 a = *(const float4*)(&As[kk][ty * 4]);
            float4 b = *(const float4*)(&Bs[kk][tx * 4]);
            acc[0][0] += a.x * b.x; acc[0][1] += a.x * b.y; acc[0][2] += a.x * b.z; acc[0][3] += a.x * b.w;
            acc[1][0] += a.y * b.x; acc[1][1] += a.y * b.y; acc[1][2] += a.y * b.z; acc[1][3] += a.y * b.w;
            acc[2][0] += a.z * b.x; acc[2][1] += a.z * b.y; acc[2][2] += a.z * b.z; acc[2][3] += a.z * b.w;
            acc[3][0] += a.w * b.x; acc[3][1] += a.w * b.y; acc[3][2] += a.w * b.z; acc[3][3] += a.w * b.w;
        }
    }
    float* Cp = C + (size_t)(m0 + ty * 4) * N + n0 + tx * 4;
#pragma unroll
    for (int i = 0; i < 4; ++i) {
        float4 v = make_float4(acc[i][0], acc[i][1], acc[i][2], acc[i][3]);
        *(float4*)(Cp + (size_t)i * N) = v;
    }
}

// ---------------- Phase 2: reservoir recurrence, data-tagged sync ---------
// Identical to round 7 EXCEPT the poll path: first K rounds use sc0 loads
// (bypass L1, read the local XCD's L2) -- if the standard bid%8->XCD
// round-robin mapping holds, group g=bid&7 is XCD-aligned and the producer's
// agent write-through store is visible in the shared local L2 at ~1/3 the
// L3 latency, with zero fabric poll traffic. Stale sc0 reads are BENIGN
// (tag mismatch -> retry); after K failed rounds we fall back to agent-scope
// loads (always fresh -> deadlock-free). K adapts per wave, clamped [1,4].
__global__ __launch_bounds__(256, 1) void resv_recur(
    const float* __restrict__ Wres,   // [1024][1024]
    float* __restrict__ out,          // [32][2048][1024] (pre-filled with u)
    ull* __restrict__ pairs)          // ws: [2 slots][32 b][1024 h] 8B pairs
{
    constexpr int H = 1024, S = 2048;
    extern __shared__ float sm[];
    float* prevL = sm;                 // [4][1024] b-major (16 KB)
    float* uL    = sm + 4096;          // [2][2048] double-buffered u (16 KB)
    float* red   = sm + 8192;          // [4 q][32 row] f4-over-b (2 KB)

    const int tid = threadIdx.x;
    const int g  = blockIdx.x & 7;
    const int r  = blockIdx.x >> 3;
    const int h0 = r * 32;
    const int b0 = g * 4;

    const int w   = tid >> 6;          // wave = k-quarter
    const int l   = tid & 63;
    const int lh  = l >> 5;            // k-half within quarter
    const int row = l & 31;            // row within this wg's 32-row block
    const int K0  = w * 256 + lh * 128;
    const int kb  = K0 >> 2;           // f4 index base

    // ---- one-time: W_res[h0+row][K0 .. K0+127] into 32 f4 registers ----
    f4 Wreg[32];
    {
        const f4* wsrc = (const f4*)(Wres + (size_t)(h0 + row) * H + K0);
#pragma unroll
        for (int i = 0; i < 32; ++i) Wreg[i] = wsrc[i];
    }

    const int fb  = tid >> 5;          // finish: batch (tid<128)
    const int frw = tid & 31;          // finish: row
    float pv = 0.f;                    // tid<128: own element's previous value
    int Kf = 4;                        // fast (sc0) poll rounds budget, [1,4]

    for (int t = 0; t < S; ++t) {
        // ---- stage u[t..t+15] into double buffer (own region, plain) ----
        if ((t & 15) == 0) {
            float* uB = uL + ((t >> 4) & 1) * 2048;
            for (int c = tid; c < 512; c += 256) {
                int rw4 = c & 7, b = (c >> 3) & 3, tt = c >> 5;
                const float4* src =
                    (const float4*)(out + ((size_t)(b0 + b) * S + (t + tt)) * H + h0);
                ((float4*)uB)[(tt * 4 + b) * 8 + rw4] = src[rw4];
            }
        }
        // ---- poll-load prev: 16 pairs/lane; sc0 fast path, agent fallback --
        {
            const ull* base = pairs + ((size_t)(t & 1) * 32 + b0) * 1024 + tid;
            const unsigned tgt = (unsigned)t;
            ull v[16];
            int tries = 0;
            for (;;) {
                if (tries < Kf) {
                    // 16 sc0 loads (local-L2 read), one waitcnt; v[c] <- base+c*256
                    asm volatile(
                        "global_load_dwordx2 %0,  %16, off sc0\n\t"
                        "global_load_dwordx2 %1,  %16, off offset:2048 sc0\n\t"
                        "global_load_dwordx2 %2,  %17, off sc0\n\t"
                        "global_load_dwordx2 %3,  %17, off offset:2048 sc0\n\t"
                        "global_load_dwordx2 %4,  %18, off sc0\n\t"
                        "global_load_dwordx2 %5,  %18, off offset:2048 sc0\n\t"
                        "global_load_dwordx2 %6,  %19, off sc0\n\t"
                        "global_load_dwordx2 %7,  %19, off offset:2048 sc0\n\t"
                        "global_load_dwordx2 %8,  %20, off sc0\n\t"
                        "global_load_dwordx2 %9,  %20, off offset:2048 sc0\n\t"
                        "global_load_dwordx2 %10, %21, off sc0\n\t"
                        "global_load_dwordx2 %11, %21, off offset:2048 sc0\n\t"
                        "global_load_dwordx2 %12, %22, off sc0\n\t"
                        "global_load_dwordx2 %13, %22, off offset:2048 sc0\n\t"
                        "global_load_dwordx2 %14, %23, off sc0\n\t"
                        "global_load_dwordx2 %15, %23, off offset:2048 sc0\n\t"
                        "s_waitcnt vmcnt(0)"
                        : "=&v"(v[0]),  "=&v"(v[1]),  "=&v"(v[2]),  "=&v"(v[3]),
                          "=&v"(v[4]),  "=&v"(v[5]),  "=&v"(v[6]),  "=&v"(v[7]),
                          "=&v"(v[8]),  "=&v"(v[9]),  "=&v"(v[10]), "=&v"(v[11]),
                          "=&v"(v[12]), "=&v"(v[13]), "=&v"(v[14]), "=&v"(v[15])
                        : "v"(base),        "v"(base + 512),  "v"(base + 1024),
                          "v"(base + 1536), "v"(base + 2048), "v"(base + 2560),
                          "v"(base + 3072), "v"(base + 3584)
                        : "memory");
                } else {
#pragma unroll
                    for (int c = 0; c < 16; ++c)
                        v[c] = __hip_atomic_load(base + c * 256, __ATOMIC_RELAXED,
                                                 __HIP_MEMORY_SCOPE_AGENT);
                }
                int ok = 1;
#pragma unroll
                for (int c = 0; c < 16; ++c)
                    ok &= ((unsigned)(v[c] >> 32) == tgt);
                if (__all(ok)) break;
                ++tries;
            }
            // adapt fast budget: shrink if we fell through to agent loads,
            // grow back otherwise (clamped [1,4]; wave-uniform by __all).
            Kf = (tries >= Kf) ? (Kf > 1 ? Kf - 1 : 1) : (Kf < 4 ? Kf + 1 : 4);
#pragma unroll
            for (int c = 0; c < 16; ++c)
                prevL[c * 256 + tid] = __uint_as_float((unsigned)v[c]);
        }
        __syncthreads();

        // ---- compute: acc[b] = sum_k W[row][k]*prev[b][k] (broadcast f4s) ----
        float a0 = 0.f, a1 = 0.f, a2 = 0.f, a3 = 0.f;
        const f4* P = (const f4*)prevL;
#pragma unroll
        for (int i = 0; i < 32; ++i) {
            f4 wv = Wreg[i];
            f4 p0 = P[kb + i];
            f4 p1 = P[256 + kb + i];
            f4 p2 = P[512 + kb + i];
            f4 p3 = P[768 + kb + i];
            a0 += wv.x * p0.x + wv.y * p0.y + wv.z * p0.z + wv.w * p0.w;
            a1 += wv.x * p1.x + wv.y * p1.y + wv.z * p1.z + wv.w * p1.w;
            a2 += wv.x * p2.x + wv.y * p2.y + wv.z * p2.z + wv.w * p2.w;
            a3 += wv.x * p3.x + wv.y * p3.y + wv.z * p3.z + wv.w * p3.w;
        }
        // combine the two k-halves (lanes l and l^32 share a row)
        a0 += __shfl_xor(a0, 32, 64);
        a1 += __shfl_xor(a1, 32, 64);
        a2 += __shfl_xor(a2, 32, 64);
        a3 += __shfl_xor(a3, 32, 64);
        if (l < 32) {
            f4 v; v.x = a0; v.y = a1; v.z = a2; v.w = a3;
            ((f4*)red)[w * 32 + row] = v;
        }
        __syncthreads();

        // ---- finish (tid<128): 1 element each; publish tagged pair ----
        if (tid < 128) {
            float sum = red[(0 * 32 + frw) * 4 + fb] + red[(1 * 32 + frw) * 4 + fb]
                      + red[(2 * 32 + frw) * 4 + fb] + red[(3 * 32 + frw) * 4 + fb];
            float uv = uL[((t >> 4) & 1) * 2048 + (((t & 15) * 4 + fb) << 5) + frw];
            float ns = LEAK * tanhf(uv + sum) + ILEAK * pv;
            pv = ns;
            ull pk = ((ull)(unsigned)(t + 1) << 32) | (ull)__float_as_uint(ns);
            __hip_atomic_store(
                pairs + ((size_t)((t + 1) & 1) * 32 + b0 + fb) * 1024 + h0 + frw,
                pk, __ATOMIC_RELAXED, __HIP_MEMORY_SCOPE_AGENT);
            out[((size_t)(b0 + fb) * S + t) * H + h0 + frw] = ns;
        }
        // no drain, no flag: consumers poll the tagged data itself.
        __syncthreads();
    }
}

extern "C" void kernel_launch(void* const* d_in, const int* in_sizes, int n_in,
                              void* d_out, int out_size, void* d_ws, size_t ws_size,
                              hipStream_t stream)
{
    const float* x    = (const float*)d_in[0];   // [32][2048][512]
    const float* Win  = (const float*)d_in[1];   // [1024][512]
    const float* Wres = (const float*)d_in[2];   // [1024][1024]
    float* out = (float*)d_out;                  // [32][2048][1024]

    ull* pairs = (ull*)d_ws;                     // 2*32*1024*8 = 524288 B

    // zero pairs every launch: (tag 0, 0.0f) == step-0 initial state
    hipMemsetAsync(d_ws, 0, 524288, stream);

    // phase 1: u = x @ W_in^T into d_out
    dim3 gemm_grid(1024 / 64, 65536 / 64);
    resv_gemm_uin<<<gemm_grid, 256, 0, stream>>>(x, Win, out, 65536, 1024, 512);

    // phase 2: recurrence. 96KB dynamic LDS pins exactly 1 wg/CU
    // (co-residency of all 256 wgs proven rounds 1-7).
    constexpr int kLds = 96 * 1024;
    hipFuncSetAttribute((const void*)resv_recur,
                        hipFuncAttributeMaxDynamicSharedMemorySize, kLds);
    resv_recur<<<dim3(256), dim3(256), kLds, stream>>>(Wres, out, pairs);
}